// Round 1
// baseline (300.057 us; speedup 1.0000x reference)
//
#include <hip/hip_runtime.h>

// Problem constants
#define B_  2
#define N_  2048
#define M_  2048
#define D_  1024
#define H_  16
#define DH_ 64

typedef __bf16 bf16x8 __attribute__((ext_vector_type(8)));
typedef float  f32x4  __attribute__((ext_vector_type(4)));

#define GAS(p) ((__attribute__((address_space(1))) void*)(p))
#define LAS(p) ((__attribute__((address_space(3))) void*)(p))

__device__ __forceinline__ unsigned short f2bf(float f) {
    unsigned int u = __builtin_bit_cast(unsigned int, f);
    u += 0x7fffu + ((u >> 16) & 1u);   // round-to-nearest-even
    return (unsigned short)(u >> 16);
}

// ---------------- kernel 1: cast x & context fp32 -> bf16 ----------------
__global__ __launch_bounds__(256) void cast_pack(
    const float* __restrict__ x, const float* __restrict__ ctx,
    unsigned short* __restrict__ xb, unsigned short* __restrict__ cb)
{
    int stride = gridDim.x * blockDim.x;
    for (int i = blockIdx.x * blockDim.x + threadIdx.x; i < 2097152; i += stride) {
        const float4* src; unsigned short* dst; int j;
        if (i < 1048576) { src = (const float4*)x;   dst = xb; j = i; }
        else             { src = (const float4*)ctx; dst = cb; j = i - 1048576; }
        float4 v = src[j];
        ushort4 o = make_ushort4(f2bf(v.x), f2bf(v.y), f2bf(v.z), f2bf(v.w));
        *(ushort4*)(dst + 4*j) = o;
    }
}

// ------------- kernel 2: transpose+cast the 4 weight matrices -------------
// in: W [1024x1024] fp32 row-major; out: W^T [1024x1024] bf16 row-major
__global__ __launch_bounds__(256) void wtrans(
    const float* __restrict__ Wq, const float* __restrict__ Wk,
    const float* __restrict__ Wv, const float* __restrict__ Wo,
    unsigned short* __restrict__ WTbase)
{
    const float* W = (blockIdx.z == 0) ? Wq : (blockIdx.z == 1) ? Wk
                    : (blockIdx.z == 2) ? Wv : Wo;
    unsigned short* WT = WTbase + (size_t)blockIdx.z * 1048576;
    __shared__ unsigned short t[32][33];
    int tx = threadIdx.x & 31, ty8 = threadIdx.x >> 5;   // 32 x 8
    int c = blockIdx.x * 32 + tx;
#pragma unroll
    for (int i = 0; i < 4; ++i) {
        int r = blockIdx.y * 32 + i*8 + ty8;
        t[i*8 + ty8][tx] = f2bf(W[(size_t)r * 1024 + c]);
    }
    __syncthreads();
    int c2 = blockIdx.y * 32 + tx;
#pragma unroll
    for (int i = 0; i < 4; ++i) {
        int r2 = blockIdx.x * 32 + i*8 + ty8;
        WT[(size_t)r2 * 1024 + c2] = t[tx][i*8 + ty8];
    }
}

// ---------------- kernel 3/5: 128x128 bf16 GEMM, C = A * Bt^T ----------------
// A: [4096 x 1024] bf16 row-major, Bt: [1024 x 1024] bf16 row-major (pre-transposed B)
// mode 0: A=xb  -> Q   stored [B,H,N,64]   (bf16)
// mode 1: A=cb  -> K   stored [B,H,M,64]   (bf16)
// mode 2: A=cb  -> V^T stored [B,H,64,M]   (bf16)
// mode 3: A=ao  -> out fp32 [B,N,1024] + bias
__global__ __launch_bounds__(256) void gemm128(
    const unsigned short* __restrict__ xb,
    const unsigned short* __restrict__ cb,
    const unsigned short* __restrict__ wT,
    const unsigned short* __restrict__ aoA,
    unsigned short* __restrict__ qkv_out,
    const float* __restrict__ bo,
    float* __restrict__ outF,
    int base_mode)
{
    __shared__ __align__(16) unsigned short As[128*32];
    __shared__ __align__(16) unsigned short Bs[128*32];

    const int mode = base_mode + blockIdx.z;
    const unsigned short* Amat = (mode == 0) ? xb : (mode == 3) ? aoA : cb;
    const unsigned short* Bt = wT + (size_t)mode * 1048576;

    const int tid = threadIdx.x;
    const int w = tid >> 6, l = tid & 63;
    const int quad = l >> 4, l16 = l & 15;
    const int wm = w & 1, wn = w >> 1;
    const int row0 = blockIdx.y * 128, col0 = blockIdx.x * 128;

    f32x4 acc[4][4];
#pragma unroll
    for (int i = 0; i < 4; ++i)
#pragma unroll
        for (int j = 0; j < 4; ++j) acc[i][j] = (f32x4){0.f, 0.f, 0.f, 0.f};

    for (int k0 = 0; k0 < 1024; k0 += 32) {
        __syncthreads();
#pragma unroll
        for (int i = 0; i < 2; ++i) {
            // chunk slot s in [0,512): row m = s>>2 (4x16B chunks per 32-elem row),
            // XOR swizzle chunk with (m>>1)&3 so frag ds_read_b128 is 2-way max.
            int s = i*256 + w*64 + l;
            int m = s >> 2, c = s & 3;
            int cs = c ^ ((m >> 1) & 3);
            __builtin_amdgcn_global_load_lds(
                GAS(Amat + (size_t)(row0 + m)*1024 + k0 + cs*8),
                LAS(As + (i*256 + w*64)*8), 16, 0, 0);
            __builtin_amdgcn_global_load_lds(
                GAS(Bt + (size_t)(col0 + m)*1024 + k0 + cs*8),
                LAS(Bs + (i*256 + w*64)*8), 16, 0, 0);
        }
        __syncthreads();

        bf16x8 af[4], bfr[4];
#pragma unroll
        for (int mt = 0; mt < 4; ++mt) {
            int m = wm*64 + mt*16 + l16;
            af[mt] = *reinterpret_cast<const bf16x8*>(As + m*32 + (quad ^ ((m >> 1) & 3))*8);
            int n = wn*64 + mt*16 + l16;
            bfr[mt] = *reinterpret_cast<const bf16x8*>(Bs + n*32 + (quad ^ ((n >> 1) & 3))*8);
        }
#pragma unroll
        for (int mt = 0; mt < 4; ++mt)
#pragma unroll
            for (int nt = 0; nt < 4; ++nt)
                acc[mt][nt] = __builtin_amdgcn_mfma_f32_16x16x32_bf16(
                    af[mt], bfr[nt], acc[mt][nt], 0, 0, 0);
    }

    // Epilogue.  C/D layout: col = lane&15, row = quad*4 + reg  [m89/m91 verified]
    if (mode == 3) {
#pragma unroll
        for (int nt = 0; nt < 4; ++nt) {
            int col = col0 + wn*64 + nt*16 + l16;
            float bv = bo[col];
#pragma unroll
            for (int mt = 0; mt < 4; ++mt) {
                int gr = row0 + wm*64 + mt*16 + quad*4;
#pragma unroll
                for (int r = 0; r < 4; ++r)
                    outF[(size_t)(gr + r)*1024 + col] = acc[mt][nt][r] + bv;
            }
        }
    } else if (mode == 2) {
        // V^T: [B,H,64,M]; 4 acc regs = 4 consecutive n -> packed ushort4 store
#pragma unroll
        for (int mt = 0; mt < 4; ++mt) {
            int gr = row0 + wm*64 + mt*16 + quad*4;
            int b = gr >> 11, nidx = gr & 2047;
#pragma unroll
            for (int nt = 0; nt < 4; ++nt) {
                int col = col0 + wn*64 + nt*16 + l16;
                int h = col >> 6, d = col & 63;
                ushort4 pk = make_ushort4(f2bf(acc[mt][nt][0]), f2bf(acc[mt][nt][1]),
                                          f2bf(acc[mt][nt][2]), f2bf(acc[mt][nt][3]));
                *(ushort4*)(qkv_out + (size_t)2*4194304
                            + (size_t)((b*16 + h)*64 + d)*2048 + nidx) = pk;
            }
        }
    } else {
        // Q/K: [B,H,seq,64]
#pragma unroll
        for (int mt = 0; mt < 4; ++mt) {
            int gr = row0 + wm*64 + mt*16 + quad*4;
#pragma unroll
            for (int nt = 0; nt < 4; ++nt) {
                int col = col0 + wn*64 + nt*16 + l16;
                int h = col >> 6, d = col & 63;
#pragma unroll
                for (int r = 0; r < 4; ++r) {
                    int grr = gr + r;
                    int b = grr >> 11, nidx = grr & 2047;
                    qkv_out[(size_t)mode*4194304
                            + (size_t)((b*16 + h)*2048 + nidx)*64 + d] = f2bf(acc[mt][nt][r]);
                }
            }
        }
    }
}

// ---------------- kernel 4: flash attention ----------------
// Q-tile 128 (4 waves x 32 rows), KV-tile 64, DH=64.
// Q frags live in registers; K and V^T staged via global_load_lds w/ XOR swizzle;
// P round-trips through per-wave LDS (C-layout -> A-layout).
__global__ __launch_bounds__(256) void flash_attn(
    const unsigned short* __restrict__ qw,   // [B,H,N,64]
    const unsigned short* __restrict__ kw,   // [B,H,M,64]
    const unsigned short* __restrict__ vtw,  // [B,H,64,M]
    unsigned short* __restrict__ ao)         // [B,N,H*64]
{
    __shared__ __align__(16) unsigned short Ks[64*64];
    __shared__ __align__(16) unsigned short Vs[64*64];
    __shared__ __align__(16) unsigned short Ps[4][32*64];

    const int tid = threadIdx.x;
    const int w = tid >> 6, l = tid & 63;
    const int quad = l >> 4, l16 = l & 15;
    const int bh = blockIdx.z * H_ + blockIdx.y;
    const int q0 = blockIdx.x * 128;

    // Q fragments: A-layout A[m=lane&15][k=quad*8+j]  [m120 verified]
    bf16x8 qf[2][2];
#pragma unroll
    for (int u = 0; u < 2; ++u)
#pragma unroll
        for (int s = 0; s < 2; ++s)
            qf[u][s] = *reinterpret_cast<const bf16x8*>(
                qw + (size_t)(bh*2048 + q0 + w*32 + u*16 + l16)*64 + s*32 + quad*8);

    float mrow[2][4], lrow[2][4];
    f32x4 accO[2][4];
#pragma unroll
    for (int u = 0; u < 2; ++u) {
#pragma unroll
        for (int r = 0; r < 4; ++r) { mrow[u][r] = -1e30f; lrow[u][r] = 0.f; }
#pragma unroll
        for (int t = 0; t < 4; ++t) accO[u][t] = (f32x4){0.f, 0.f, 0.f, 0.f};
    }

    const float cscale = 0.125f * 1.44269504088896340736f;  // SCALE * log2(e)
    unsigned short* Pw = &Ps[w][0];

    for (int kv0 = 0; kv0 < M_; kv0 += 64) {
        __syncthreads();
#pragma unroll
        for (int i = 0; i < 2; ++i) {
            // 64x64 bf16 tile = 512 16B chunks, 8 chunks/row; swizzle c ^= (row&7)
            int s = i*256 + w*64 + l;
            int m = s >> 3, c = s & 7;
            int cs = c ^ (m & 7);
            __builtin_amdgcn_global_load_lds(
                GAS(kw + (size_t)(bh*2048 + kv0 + m)*64 + cs*8),
                LAS(Ks + (i*256 + w*64)*8), 16, 0, 0);
            __builtin_amdgcn_global_load_lds(
                GAS(vtw + (size_t)(bh*64 + m)*2048 + kv0 + cs*8),
                LAS(Vs + (i*256 + w*64)*8), 16, 0, 0);
        }
        __syncthreads();

        // S = Q K^T : B-frag = K_lds[m=lane&15][d-chunk], rows t*16+l16
        f32x4 sac[2][4];
#pragma unroll
        for (int u = 0; u < 2; ++u)
#pragma unroll
            for (int t = 0; t < 4; ++t) sac[u][t] = (f32x4){0.f, 0.f, 0.f, 0.f};
#pragma unroll
        for (int s = 0; s < 2; ++s) {
#pragma unroll
            for (int t = 0; t < 4; ++t) {
                bf16x8 kf = *reinterpret_cast<const bf16x8*>(
                    Ks + (t*16 + l16)*64 + ((s*4 + quad) ^ (l16 & 7))*8);
                sac[0][t] = __builtin_amdgcn_mfma_f32_16x16x32_bf16(qf[0][s], kf, sac[0][t], 0, 0, 0);
                sac[1][t] = __builtin_amdgcn_mfma_f32_16x16x32_bf16(qf[1][s], kf, sac[1][t], 0, 0, 0);
            }
        }

        // online softmax + write P (bf16) to per-wave LDS
#pragma unroll
        for (int u = 0; u < 2; ++u) {
#pragma unroll
            for (int t = 0; t < 4; ++t)
#pragma unroll
                for (int r = 0; r < 4; ++r) sac[u][t][r] *= cscale;
#pragma unroll
            for (int r = 0; r < 4; ++r) {
                float m0 = fmaxf(fmaxf(sac[u][0][r], sac[u][1][r]),
                                 fmaxf(sac[u][2][r], sac[u][3][r]));
                m0 = fmaxf(m0, __shfl_xor(m0, 1));
                m0 = fmaxf(m0, __shfl_xor(m0, 2));
                m0 = fmaxf(m0, __shfl_xor(m0, 4));
                m0 = fmaxf(m0, __shfl_xor(m0, 8));
                float mn = fmaxf(mrow[u][r], m0);
                float al = exp2f(mrow[u][r] - mn);
                mrow[u][r] = mn;
                float ps = 0.f;
#pragma unroll
                for (int t = 0; t < 4; ++t) {
                    float p = exp2f(sac[u][t][r] - mn);
                    sac[u][t][r] = p;
                    ps += p;
                }
                ps += __shfl_xor(ps, 1);
                ps += __shfl_xor(ps, 2);
                ps += __shfl_xor(ps, 4);
                ps += __shfl_xor(ps, 8);
                lrow[u][r] = lrow[u][r]*al + ps;
#pragma unroll
                for (int td = 0; td < 4; ++td) accO[u][td][r] *= al;
            }
            // P write: row rp = u*16+quad*4+r, col = t*16+l16, same XOR swizzle
#pragma unroll
            for (int t = 0; t < 4; ++t)
#pragma unroll
                for (int r = 0; r < 4; ++r) {
                    int rp = u*16 + quad*4 + r;
                    int col = t*16 + l16;
                    int cch = col >> 3;
                    Pw[rp*64 + ((cch ^ (rp & 7)))*8 + (col & 7)] = f2bf(sac[u][t][r]);
                }
        }

        // O += P V : A-frag from Pw, B-frag from Vs (V^T rows = d)
        bf16x8 pf[2][2];
#pragma unroll
        for (int u = 0; u < 2; ++u)
#pragma unroll
            for (int s = 0; s < 2; ++s)
                pf[u][s] = *reinterpret_cast<const bf16x8*>(
                    Pw + (u*16 + l16)*64 + ((s*4 + quad) ^ (l16 & 7))*8);
#pragma unroll
        for (int td = 0; td < 4; ++td)
#pragma unroll
            for (int s = 0; s < 2; ++s) {
                bf16x8 vf = *reinterpret_cast<const bf16x8*>(
                    Vs + (td*16 + l16)*64 + ((s*4 + quad) ^ (l16 & 7))*8);
                accO[0][td] = __builtin_amdgcn_mfma_f32_16x16x32_bf16(pf[0][s], vf, accO[0][td], 0, 0, 0);
                accO[1][td] = __builtin_amdgcn_mfma_f32_16x16x32_bf16(pf[1][s], vf, accO[1][td], 0, 0, 0);
            }
    }

    // epilogue: O /= l, write ao [B,N,H*64] bf16
#pragma unroll
    for (int u = 0; u < 2; ++u) {
        float inv[4];
#pragma unroll
        for (int r = 0; r < 4; ++r) inv[r] = 1.f / lrow[u][r];
#pragma unroll
        for (int td = 0; td < 4; ++td)
#pragma unroll
            for (int r = 0; r < 4; ++r) {
                int qrow = q0 + w*32 + u*16 + quad*4 + r;
                ao[(size_t)(blockIdx.z*2048 + qrow)*1024 + blockIdx.y*64 + td*16 + l16]
                    = f2bf(accO[u][td][r] * inv[r]);
            }
    }
}

extern "C" void kernel_launch(void* const* d_in, const int* in_sizes, int n_in,
                              void* d_out, int out_size, void* d_ws, size_t ws_size,
                              hipStream_t stream)
{
    const float* x   = (const float*)d_in[0];
    const float* ctx = (const float*)d_in[1];
    const float* Wq  = (const float*)d_in[2];
    const float* Wk  = (const float*)d_in[3];
    const float* Wv  = (const float*)d_in[4];
    const float* Wo  = (const float*)d_in[5];
    const float* bo  = (const float*)d_in[6];
    float* out = (float*)d_out;

    // workspace layout (ushort elements):
    //   [0       , 4194304 )  xb  (bf16 x)   -- later reused as ao (flash output)
    //   [4194304 , 8388608 )  cb  (bf16 context)
    //   [8388608 , 12582912)  wT  (Wq^T,Wk^T,Wv^T,Wo^T bf16, 1048576 each)
    //   [12582912, 25165824)  qkv (Q, K, V^T bf16, 4194304 each)
    // total 50.3 MB
    unsigned short* ws  = (unsigned short*)d_ws;
    unsigned short* xb  = ws;
    unsigned short* cb  = ws + 4194304;
    unsigned short* wT  = ws + 8388608;
    unsigned short* qkv = ws + 12582912;
    unsigned short* ao  = ws;  // reuse xb space (xb dead after projections)

    cast_pack<<<dim3(1024), dim3(256), 0, stream>>>(x, ctx, xb, cb);
    wtrans<<<dim3(32, 32, 4), dim3(256), 0, stream>>>(Wq, Wk, Wv, Wo, wT);
    gemm128<<<dim3(8, 32, 3), dim3(256), 0, stream>>>(xb, cb, wT, ao, qkv, bo, out, 0);
    flash_attn<<<dim3(16, 16, 2), dim3(256), 0, stream>>>(qkv, qkv + 4194304, qkv + 8388608, ao);
    gemm128<<<dim3(8, 32, 1), dim3(256), 0, stream>>>(xb, cb, wT, ao, qkv, bo, out, 3);
}

// Round 2
// 252.461 us; speedup vs baseline: 1.1885x; 1.1885x over previous
//
#include <hip/hip_runtime.h>

// Problem constants
#define B_  2
#define N_  2048
#define M_  2048
#define D_  1024
#define H_  16
#define DH_ 64

typedef __bf16 bf16x8 __attribute__((ext_vector_type(8)));
typedef __bf16 bf16x4 __attribute__((ext_vector_type(4)));
typedef short  short4v __attribute__((ext_vector_type(4)));
typedef float  f32x4  __attribute__((ext_vector_type(4)));

#define GAS(p) ((__attribute__((address_space(1))) void*)(p))
#define LAS(p) ((__attribute__((address_space(3))) void*)(p))

__device__ __forceinline__ unsigned short f2bf(float f) {
    unsigned int u = __builtin_bit_cast(unsigned int, f);
    u += 0x7fffu + ((u >> 16) & 1u);   // round-to-nearest-even
    return (unsigned short)(u >> 16);
}

// ---------------- kernel 1: cast x & context fp32 -> bf16 ----------------
__global__ __launch_bounds__(256) void cast_pack(
    const float* __restrict__ x, const float* __restrict__ ctx,
    unsigned short* __restrict__ xb, unsigned short* __restrict__ cb)
{
    int stride = gridDim.x * blockDim.x;
    for (int i = blockIdx.x * blockDim.x + threadIdx.x; i < 2097152; i += stride) {
        const float4* src; unsigned short* dst; int j;
        if (i < 1048576) { src = (const float4*)x;   dst = xb; j = i; }
        else             { src = (const float4*)ctx; dst = cb; j = i - 1048576; }
        float4 v = src[j];
        ushort4 o = make_ushort4(f2bf(v.x), f2bf(v.y), f2bf(v.z), f2bf(v.w));
        *(ushort4*)(dst + 4*j) = o;
    }
}

// ------------- kernel 2: transpose+cast the 4 weight matrices -------------
__global__ __launch_bounds__(256) void wtrans(
    const float* __restrict__ Wq, const float* __restrict__ Wk,
    const float* __restrict__ Wv, const float* __restrict__ Wo,
    unsigned short* __restrict__ WTbase)
{
    const float* W = (blockIdx.z == 0) ? Wq : (blockIdx.z == 1) ? Wk
                    : (blockIdx.z == 2) ? Wv : Wo;
    unsigned short* WT = WTbase + (size_t)blockIdx.z * 1048576;
    __shared__ unsigned short t[32][33];
    int tx = threadIdx.x & 31, ty8 = threadIdx.x >> 5;   // 32 x 8
    int c = blockIdx.x * 32 + tx;
#pragma unroll
    for (int i = 0; i < 4; ++i) {
        int r = blockIdx.y * 32 + i*8 + ty8;
        t[i*8 + ty8][tx] = f2bf(W[(size_t)r * 1024 + c]);
    }
    __syncthreads();
    int c2 = blockIdx.y * 32 + tx;
#pragma unroll
    for (int i = 0; i < 4; ++i) {
        int r2 = blockIdx.x * 32 + i*8 + ty8;
        WT[(size_t)r2 * 1024 + c2] = t[tx][i*8 + ty8];
    }
}

// ---------------- kernel 3/5: 128x128 bf16 GEMM, C = A * Bt^T ----------------
// mode 0: A=xb  -> Q   stored [B,H,N,64]   (bf16)
// mode 1: A=cb  -> K   stored [B,H,M,64]   (bf16)
// mode 2: A=cb  -> V^T stored [B,H,64,M]   (bf16)
// mode 3: A=ao  -> out fp32 [B,N,1024] + bias
__global__ __launch_bounds__(256) void gemm128(
    const unsigned short* __restrict__ xb,
    const unsigned short* __restrict__ cb,
    const unsigned short* __restrict__ wT,
    const unsigned short* __restrict__ aoA,
    unsigned short* __restrict__ qkv_out,
    const float* __restrict__ bo,
    float* __restrict__ outF,
    int base_mode)
{
    __shared__ __align__(16) unsigned short As[128*32];
    __shared__ __align__(16) unsigned short Bs[128*32];

    const int mode = base_mode + blockIdx.z;
    const unsigned short* Amat = (mode == 0) ? xb : (mode == 3) ? aoA : cb;
    const unsigned short* Bt = wT + (size_t)mode * 1048576;

    const int tid = threadIdx.x;
    const int w = tid >> 6, l = tid & 63;
    const int quad = l >> 4, l16 = l & 15;
    const int wm = w & 1, wn = w >> 1;
    const int row0 = blockIdx.y * 128, col0 = blockIdx.x * 128;

    f32x4 acc[4][4];
#pragma unroll
    for (int i = 0; i < 4; ++i)
#pragma unroll
        for (int j = 0; j < 4; ++j) acc[i][j] = (f32x4){0.f, 0.f, 0.f, 0.f};

    for (int k0 = 0; k0 < 1024; k0 += 32) {
        __syncthreads();
#pragma unroll
        for (int i = 0; i < 2; ++i) {
            int s = i*256 + w*64 + l;
            int m = s >> 2, c = s & 3;
            int cs = c ^ ((m >> 1) & 3);
            __builtin_amdgcn_global_load_lds(
                GAS(Amat + (size_t)(row0 + m)*1024 + k0 + cs*8),
                LAS(As + (i*256 + w*64)*8), 16, 0, 0);
            __builtin_amdgcn_global_load_lds(
                GAS(Bt + (size_t)(col0 + m)*1024 + k0 + cs*8),
                LAS(Bs + (i*256 + w*64)*8), 16, 0, 0);
        }
        __syncthreads();

        bf16x8 af[4], bfr[4];
#pragma unroll
        for (int mt = 0; mt < 4; ++mt) {
            int m = wm*64 + mt*16 + l16;
            af[mt] = *reinterpret_cast<const bf16x8*>(As + m*32 + (quad ^ ((m >> 1) & 3))*8);
            int n = wn*64 + mt*16 + l16;
            bfr[mt] = *reinterpret_cast<const bf16x8*>(Bs + n*32 + (quad ^ ((n >> 1) & 3))*8);
        }
#pragma unroll
        for (int mt = 0; mt < 4; ++mt)
#pragma unroll
            for (int nt = 0; nt < 4; ++nt)
                acc[mt][nt] = __builtin_amdgcn_mfma_f32_16x16x32_bf16(
                    af[mt], bfr[nt], acc[mt][nt], 0, 0, 0);
    }

    if (mode == 3) {
#pragma unroll
        for (int nt = 0; nt < 4; ++nt) {
            int col = col0 + wn*64 + nt*16 + l16;
            float bv = bo[col];
#pragma unroll
            for (int mt = 0; mt < 4; ++mt) {
                int gr = row0 + wm*64 + mt*16 + quad*4;
#pragma unroll
                for (int r = 0; r < 4; ++r)
                    outF[(size_t)(gr + r)*1024 + col] = acc[mt][nt][r] + bv;
            }
        }
    } else if (mode == 2) {
        // V^T: [B,H,64,M]
#pragma unroll
        for (int mt = 0; mt < 4; ++mt) {
            int gr = row0 + wm*64 + mt*16 + quad*4;
            int b = gr >> 11, nidx = gr & 2047;
#pragma unroll
            for (int nt = 0; nt < 4; ++nt) {
                int col = col0 + wn*64 + nt*16 + l16;
                int h = col >> 6, d = col & 63;
                ushort4 pk = make_ushort4(f2bf(acc[mt][nt][0]), f2bf(acc[mt][nt][1]),
                                          f2bf(acc[mt][nt][2]), f2bf(acc[mt][nt][3]));
                *(ushort4*)(qkv_out + (size_t)2*4194304
                            + (size_t)((b*16 + h)*64 + d)*2048 + nidx) = pk;
            }
        }
    } else {
        // Q/K: [B,H,seq,64]
#pragma unroll
        for (int mt = 0; mt < 4; ++mt) {
            int gr = row0 + wm*64 + mt*16 + quad*4;
#pragma unroll
            for (int nt = 0; nt < 4; ++nt) {
                int col = col0 + wn*64 + nt*16 + l16;
                int h = col >> 6, d = col & 63;
#pragma unroll
                for (int r = 0; r < 4; ++r) {
                    int grr = gr + r;
                    int b = grr >> 11, nidx = grr & 2047;
                    qkv_out[(size_t)mode*4194304
                            + (size_t)((b*16 + h)*2048 + nidx)*64 + d] = f2bf(acc[mt][nt][r]);
                }
            }
        }
    }
}

// ---------------- kernel 4: flash attention (S^T operand-swap form) -----------
// Per block: q-tile 64 (4 waves x 16 q), KV-tile 128.
// S^T = K Q^T  -> C-layout col=q=l16, row=kv=quad*4+r  == B-frag layout of
// mfma_16x16x16, so P^T feeds O^T = V^T P^T straight from registers.
__global__ __launch_bounds__(256) void flash_attn(
    const unsigned short* __restrict__ qw,   // [B,H,N,64]
    const unsigned short* __restrict__ kw,   // [B,H,M,64]
    const unsigned short* __restrict__ vtw,  // [B,H,64,M]
    unsigned short* __restrict__ ao)         // [B,N,H*64]
{
    __shared__ __align__(16) unsigned short Ks[128*64];  // rows=kv (128B, 8 chunks)
    __shared__ __align__(16) unsigned short Vs[64*128];  // rows=d (256B, 16 chunks)

    const int tid = threadIdx.x;
    const int w = tid >> 6, l = tid & 63;
    const int quad = l >> 4, l16 = l & 15;
    const int bh = blockIdx.z * H_ + blockIdx.y;
    const int q0 = blockIdx.x * 64 + w * 16;   // this wave's 16 queries

    // Q as B-frag (K=32): B[n=q=l16][k=d=s*32+quad*8+j]
    bf16x8 qf[2];
#pragma unroll
    for (int s = 0; s < 2; ++s)
        qf[s] = *reinterpret_cast<const bf16x8*>(
            qw + (size_t)(bh*2048 + q0 + l16)*64 + s*32 + quad*8);

    float mold = -1e30f, lsum = 0.f;
    f32x4 accO[4];   // O^T[d=td*16+quad*4+r][q=l16]
#pragma unroll
    for (int td = 0; td < 4; ++td) accO[td] = (f32x4){0.f, 0.f, 0.f, 0.f};

    const float cscale = 0.125f * 1.44269504088896340736f;  // SCALE * log2(e)

    for (int kv0 = 0; kv0 < M_; kv0 += 128) {
        __syncthreads();
#pragma unroll
        for (int i = 0; i < 4; ++i) {
            int base = i*256 + w*64;          // wave-uniform slot base
            int n = base + l;                 // this lane's 16B chunk slot
            // Ks: slot (kv, c) holds global chunk (kv, c ^ (kv&7))
            int kv = n >> 3, c = n & 7;
            __builtin_amdgcn_global_load_lds(
                GAS(kw + (size_t)(bh*2048 + kv0 + kv)*64 + (c ^ (kv & 7))*8),
                LAS(Ks + base*8), 16, 0, 0);
            // Vs: slot (d, c) holds global chunk (d, c ^ (d&15))
            int d = n >> 4, c2 = n & 15;
            __builtin_amdgcn_global_load_lds(
                GAS(vtw + (size_t)(bh*64 + d)*2048 + kv0 + (c2 ^ (d & 15))*8),
                LAS(Vs + base*8), 16, 0, 0);
        }
        __syncthreads();

        // S^T = K Q^T : A = K-frag (m=kv), B = Q-frag (n=q)
        f32x4 sac[8];
#pragma unroll
        for (int t = 0; t < 8; ++t) sac[t] = (f32x4){0.f, 0.f, 0.f, 0.f};
#pragma unroll
        for (int s = 0; s < 2; ++s)
#pragma unroll
            for (int t = 0; t < 8; ++t) {
                bf16x8 kf = *reinterpret_cast<const bf16x8*>(
                    Ks + (t*16 + l16)*64 + (((s*4 + quad) ^ (l16 & 7))*8));
                sac[t] = __builtin_amdgcn_mfma_f32_16x16x32_bf16(kf, qf[s], sac[t], 0, 0, 0);
            }

        // online softmax: state is per-q = per-lane scalar
        float mx = sac[0][0];
#pragma unroll
        for (int t = 0; t < 8; ++t)
#pragma unroll
            for (int r = 0; r < 4; ++r) mx = fmaxf(mx, sac[t][r]);
        mx = fmaxf(mx, __shfl_xor(mx, 16));
        mx = fmaxf(mx, __shfl_xor(mx, 32));
        float mn = fmaxf(mold, mx * cscale);
        float al = exp2f(mold - mn);
        mold = mn;

        float ps0 = 0.f, ps1 = 0.f, ps2 = 0.f, ps3 = 0.f;
        short4v pk[8];
#pragma unroll
        for (int t = 0; t < 8; ++t) {
            bf16x4 pb;
            {
                float p0 = exp2f(fmaf(sac[t][0], cscale, -mn));
                float p1 = exp2f(fmaf(sac[t][1], cscale, -mn));
                float p2 = exp2f(fmaf(sac[t][2], cscale, -mn));
                float p3 = exp2f(fmaf(sac[t][3], cscale, -mn));
                ps0 += p0; ps1 += p1; ps2 += p2; ps3 += p3;
                pb[0] = (__bf16)p0; pb[1] = (__bf16)p1;
                pb[2] = (__bf16)p2; pb[3] = (__bf16)p3;
            }
            pk[t] = __builtin_bit_cast(short4v, pb);
        }
        float ps = (ps0 + ps1) + (ps2 + ps3);
        ps += __shfl_xor(ps, 16);
        ps += __shfl_xor(ps, 32);
        lsum = lsum * al + ps;

#pragma unroll
        for (int td = 0; td < 4; ++td)
#pragma unroll
            for (int r = 0; r < 4; ++r) accO[td][r] *= al;

        // O^T += V^T P^T : A = V^T-frag (m=d, k=kv), B = P^T (from registers)
#pragma unroll
        for (int td = 0; td < 4; ++td)
#pragma unroll
            for (int t = 0; t < 8; ++t) {
                short4v vf = *reinterpret_cast<const short4v*>(
                    Vs + (td*16 + l16)*128
                       + (((t*2 + (quad >> 1)) ^ l16) & 15)*8 + (quad & 1)*4);
                accO[td] = __builtin_amdgcn_mfma_f32_16x16x16bf16_1k(
                    vf, pk[t], accO[td], 0, 0, 0);
            }
    }

    // epilogue: O = O^T / l, write ao [B,N,H*64] bf16
    float inv = 1.f / lsum;   // per q = per lane
    const size_t rowbase = (size_t)(blockIdx.z*2048 + q0 + l16)*1024 + blockIdx.y*64;
#pragma unroll
    for (int td = 0; td < 4; ++td)
#pragma unroll
        for (int r = 0; r < 4; ++r) {
            int d = td*16 + quad*4 + r;
            ao[rowbase + d] = f2bf(accO[td][r] * inv);
        }
}

extern "C" void kernel_launch(void* const* d_in, const int* in_sizes, int n_in,
                              void* d_out, int out_size, void* d_ws, size_t ws_size,
                              hipStream_t stream)
{
    const float* x   = (const float*)d_in[0];
    const float* ctx = (const float*)d_in[1];
    const float* Wq  = (const float*)d_in[2];
    const float* Wk  = (const float*)d_in[3];
    const float* Wv  = (const float*)d_in[4];
    const float* Wo  = (const float*)d_in[5];
    const float* bo  = (const float*)d_in[6];
    float* out = (float*)d_out;

    unsigned short* ws  = (unsigned short*)d_ws;
    unsigned short* xb  = ws;
    unsigned short* cb  = ws + 4194304;
    unsigned short* wT  = ws + 8388608;
    unsigned short* qkv = ws + 12582912;
    unsigned short* ao  = ws;  // reuse xb space (xb dead after projections)

    cast_pack<<<dim3(1024), dim3(256), 0, stream>>>(x, ctx, xb, cb);
    wtrans<<<dim3(32, 32, 4), dim3(256), 0, stream>>>(Wq, Wk, Wv, Wo, wT);
    gemm128<<<dim3(8, 32, 3), dim3(256), 0, stream>>>(xb, cb, wT, ao, qkv, bo, out, 0);
    flash_attn<<<dim3(32, 16, 2), dim3(256), 0, stream>>>(qkv, qkv + 4194304, qkv + 8388608, ao);
    gemm128<<<dim3(8, 32, 1), dim3(256), 0, stream>>>(xb, cb, wT, ao, qkv, bo, out, 3);
}

// Round 3
// 233.192 us; speedup vs baseline: 1.2867x; 1.0826x over previous
//
#include <hip/hip_runtime.h>

// Problem constants
#define B_  2
#define N_  2048
#define M_  2048
#define D_  1024
#define H_  16
#define DH_ 64

typedef __bf16 bf16x8 __attribute__((ext_vector_type(8)));
typedef __bf16 bf16x4 __attribute__((ext_vector_type(4)));
typedef short  short4v __attribute__((ext_vector_type(4)));
typedef float  f32x4  __attribute__((ext_vector_type(4)));

#define GAS(p) ((__attribute__((address_space(1))) void*)(p))
#define LAS(p) ((__attribute__((address_space(3))) void*)(p))

// SCALE * log2(e), folded into Q at projection time
#define QPRESCALE 0.18033688011112042f

__device__ __forceinline__ unsigned short f2bf(float f) {
    unsigned int u = __builtin_bit_cast(unsigned int, f);
    u += 0x7fffu + ((u >> 16) & 1u);   // round-to-nearest-even
    return (unsigned short)(u >> 16);
}

// ------- kernel 1: prep = weight transpose+cast (z<4) | input cast (z==4) -------
__global__ __launch_bounds__(256) void prep(
    const float* __restrict__ x, const float* __restrict__ ctx,
    const float* __restrict__ Wq, const float* __restrict__ Wk,
    const float* __restrict__ Wv, const float* __restrict__ Wo,
    unsigned short* __restrict__ xb, unsigned short* __restrict__ cb,
    unsigned short* __restrict__ WTbase)
{
    if (blockIdx.z == 4) {
        // cast x & context fp32 -> bf16, float4-vectorized
        int blk = blockIdx.y * 32 + blockIdx.x;
        int stride = 1024 * 256;
        for (int i = blk * 256 + threadIdx.x; i < 2097152; i += stride) {
            const float4* src; unsigned short* dst; int j;
            if (i < 1048576) { src = (const float4*)x;   dst = xb; j = i; }
            else             { src = (const float4*)ctx; dst = cb; j = i - 1048576; }
            float4 v = src[j];
            ushort4 o = make_ushort4(f2bf(v.x), f2bf(v.y), f2bf(v.z), f2bf(v.w));
            *(ushort4*)(dst + 4*j) = o;
        }
        return;
    }
    const float* W = (blockIdx.z == 0) ? Wq : (blockIdx.z == 1) ? Wk
                    : (blockIdx.z == 2) ? Wv : Wo;
    unsigned short* WT = WTbase + (size_t)blockIdx.z * 1048576;
    __shared__ unsigned short t[32][33];
    int tx = threadIdx.x & 31, ty8 = threadIdx.x >> 5;   // 32 x 8
    int c = blockIdx.x * 32 + tx;
#pragma unroll
    for (int i = 0; i < 4; ++i) {
        int r = blockIdx.y * 32 + i*8 + ty8;
        t[i*8 + ty8][tx] = f2bf(W[(size_t)r * 1024 + c]);
    }
    __syncthreads();
    int c2 = blockIdx.y * 32 + tx;
#pragma unroll
    for (int i = 0; i < 4; ++i) {
        int r2 = blockIdx.x * 32 + i*8 + ty8;
        WT[(size_t)r2 * 1024 + c2] = t[tx][i*8 + ty8];
    }
}

// ---------------- kernel 2/4: 128x128 bf16 GEMM, C = A * Bt^T ----------------
// mode 0: A=xb  -> Q*QPRESCALE stored [B,H,N,64] (bf16)
// mode 1: A=cb  -> K   stored [B,H,M,64]   (bf16)
// mode 2: A=cb  -> V^T stored [B,H,64,M]   (bf16)
// mode 3: A=ao  -> out fp32 [B,N,1024] + bias
__global__ __launch_bounds__(256) void gemm128(
    const unsigned short* __restrict__ xb,
    const unsigned short* __restrict__ cb,
    const unsigned short* __restrict__ wT,
    const unsigned short* __restrict__ aoA,
    unsigned short* __restrict__ qkv_out,
    const float* __restrict__ bo,
    float* __restrict__ outF,
    int base_mode)
{
    __shared__ __align__(16) unsigned short As[128*32];
    __shared__ __align__(16) unsigned short Bs[128*32];

    const int mode = base_mode + blockIdx.z;
    const unsigned short* Amat = (mode == 0) ? xb : (mode == 3) ? aoA : cb;
    const unsigned short* Bt = wT + (size_t)mode * 1048576;

    const int tid = threadIdx.x;
    const int w = tid >> 6, l = tid & 63;
    const int quad = l >> 4, l16 = l & 15;
    const int wm = w & 1, wn = w >> 1;
    const int row0 = blockIdx.y * 128, col0 = blockIdx.x * 128;

    f32x4 acc[4][4];
#pragma unroll
    for (int i = 0; i < 4; ++i)
#pragma unroll
        for (int j = 0; j < 4; ++j) acc[i][j] = (f32x4){0.f, 0.f, 0.f, 0.f};

    for (int k0 = 0; k0 < 1024; k0 += 32) {
        __syncthreads();
#pragma unroll
        for (int i = 0; i < 2; ++i) {
            int s = i*256 + w*64 + l;
            int m = s >> 2, c = s & 3;
            int cs = c ^ ((m >> 1) & 3);
            __builtin_amdgcn_global_load_lds(
                GAS(Amat + (size_t)(row0 + m)*1024 + k0 + cs*8),
                LAS(As + (i*256 + w*64)*8), 16, 0, 0);
            __builtin_amdgcn_global_load_lds(
                GAS(Bt + (size_t)(col0 + m)*1024 + k0 + cs*8),
                LAS(Bs + (i*256 + w*64)*8), 16, 0, 0);
        }
        __syncthreads();

        bf16x8 af[4], bfr[4];
#pragma unroll
        for (int mt = 0; mt < 4; ++mt) {
            int m = wm*64 + mt*16 + l16;
            af[mt] = *reinterpret_cast<const bf16x8*>(As + m*32 + (quad ^ ((m >> 1) & 3))*8);
            int n = wn*64 + mt*16 + l16;
            bfr[mt] = *reinterpret_cast<const bf16x8*>(Bs + n*32 + (quad ^ ((n >> 1) & 3))*8);
        }
#pragma unroll
        for (int mt = 0; mt < 4; ++mt)
#pragma unroll
            for (int nt = 0; nt < 4; ++nt)
                acc[mt][nt] = __builtin_amdgcn_mfma_f32_16x16x32_bf16(
                    af[mt], bfr[nt], acc[mt][nt], 0, 0, 0);
    }

    if (mode == 3) {
#pragma unroll
        for (int nt = 0; nt < 4; ++nt) {
            int col = col0 + wn*64 + nt*16 + l16;
            float bv = bo[col];
#pragma unroll
            for (int mt = 0; mt < 4; ++mt) {
                int gr = row0 + wm*64 + mt*16 + quad*4;
#pragma unroll
                for (int r = 0; r < 4; ++r)
                    outF[(size_t)(gr + r)*1024 + col] = acc[mt][nt][r] + bv;
            }
        }
    } else if (mode == 2) {
        // V^T: [B,H,64,M]
#pragma unroll
        for (int mt = 0; mt < 4; ++mt) {
            int gr = row0 + wm*64 + mt*16 + quad*4;
            int b = gr >> 11, nidx = gr & 2047;
#pragma unroll
            for (int nt = 0; nt < 4; ++nt) {
                int col = col0 + wn*64 + nt*16 + l16;
                int h = col >> 6, d = col & 63;
                ushort4 pk = make_ushort4(f2bf(acc[mt][nt][0]), f2bf(acc[mt][nt][1]),
                                          f2bf(acc[mt][nt][2]), f2bf(acc[mt][nt][3]));
                *(ushort4*)(qkv_out + (size_t)2*4194304
                            + (size_t)((b*16 + h)*64 + d)*2048 + nidx) = pk;
            }
        }
    } else {
        // Q/K: [B,H,seq,64]; Q is pre-scaled by SCALE*log2(e)
        const float qs = (mode == 0) ? QPRESCALE : 1.0f;
#pragma unroll
        for (int mt = 0; mt < 4; ++mt) {
            int gr = row0 + wm*64 + mt*16 + quad*4;
#pragma unroll
            for (int nt = 0; nt < 4; ++nt) {
                int col = col0 + wn*64 + nt*16 + l16;
                int h = col >> 6, d = col & 63;
#pragma unroll
                for (int r = 0; r < 4; ++r) {
                    int grr = gr + r;
                    int b = grr >> 11, nidx = grr & 2047;
                    qkv_out[(size_t)mode*4194304
                            + (size_t)((b*16 + h)*2048 + nidx)*64 + d]
                        = f2bf(acc[mt][nt][r] * qs);
                }
            }
        }
    }
}

// ---------------- kernel 3: flash attention (shift-free softmax) ----------------
// Per block: q-tile 128 (4 waves x 32 q), KV-tile 128.
// S^T = K Q^T (C-layout == 16x16x16 B-frag layout) -> P^T feeds O^T = V^T P^T
// straight from registers.  Softmax denominator computed by MFMA against 16
// all-ones rows appended to the V^T tile -> zero cross-lane ops in the kernel.
// Scores are pre-scaled (Q carries SCALE*log2e), bounded |s|<~4, so the
// max-shift is unnecessary: p = exp2(s) raw, sum/normalize at the end.
__global__ __launch_bounds__(256, 2) void flash_attn(
    const unsigned short* __restrict__ qw,   // [B,H,N,64]  (pre-scaled)
    const unsigned short* __restrict__ kw,   // [B,H,M,64]
    const unsigned short* __restrict__ vtw,  // [B,H,64,M]
    unsigned short* __restrict__ ao)         // [B,N,H*64]
{
    __shared__ __align__(16) unsigned short Ks[128*64];  // rows=kv (128B, 8 chunks)
    __shared__ __align__(16) unsigned short Vs[80*128];  // rows=d (256B); rows 64..79 = 1.0

    const int tid = threadIdx.x;
    const int w = tid >> 6, l = tid & 63;
    const int quad = l >> 4, l16 = l & 15;
    const int bh = blockIdx.z * H_ + blockIdx.y;
    const int q0 = blockIdx.x * 128 + w * 32;   // this wave's 32 queries

    // ones rows (sum tile), written once; staging never touches rows >= 64
    {
        const unsigned int ONE2 = 0x3F803F80u;
        *((uint4*)(Vs + 64*128) + tid) = make_uint4(ONE2, ONE2, ONE2, ONE2);
    }

    // Q as B-frag (K=32): B[n=q][k=d]; two 16-q groups
    bf16x8 qf[2][2];
#pragma unroll
    for (int qg = 0; qg < 2; ++qg)
#pragma unroll
        for (int s = 0; s < 2; ++s)
            qf[qg][s] = *reinterpret_cast<const bf16x8*>(
                qw + (size_t)(bh*2048 + q0 + qg*16 + l16)*64 + s*32 + quad*8);

    f32x4 accO[2][5];   // [qg][td]; td=4 is the softmax-sum tile
#pragma unroll
    for (int qg = 0; qg < 2; ++qg)
#pragma unroll
        for (int td = 0; td < 5; ++td) accO[qg][td] = (f32x4){0.f, 0.f, 0.f, 0.f};

    for (int kv0 = 0; kv0 < M_; kv0 += 128) {
        __syncthreads();
#pragma unroll
        for (int i = 0; i < 4; ++i) {
            int base = i*256 + w*64;          // wave-uniform slot base
            int n = base + l;
            // Ks: slot (kv, c) holds global chunk (kv, c ^ (kv&7))
            int kv = n >> 3, ck = n & 7;
            __builtin_amdgcn_global_load_lds(
                GAS(kw + (size_t)(bh*2048 + kv0 + kv)*64 + (ck ^ (kv & 7))*8),
                LAS(Ks + base*8), 16, 0, 0);
            // Vs: slot (d, c) holds global chunk (d, c ^ (d&15))
            int d = n >> 4, cv = n & 15;
            __builtin_amdgcn_global_load_lds(
                GAS(vtw + (size_t)(bh*64 + d)*2048 + kv0 + (cv ^ (d & 15))*8),
                LAS(Vs + base*8), 16, 0, 0);
        }
        __syncthreads();

        // S^T = K Q^T : A = K-frag (m=kv), B = Q-frag (n=q)
        f32x4 sac[2][8];
#pragma unroll
        for (int qg = 0; qg < 2; ++qg)
#pragma unroll
            for (int t = 0; t < 8; ++t) sac[qg][t] = (f32x4){0.f, 0.f, 0.f, 0.f};
#pragma unroll
        for (int s = 0; s < 2; ++s)
#pragma unroll
            for (int t = 0; t < 8; ++t) {
                bf16x8 kf = *reinterpret_cast<const bf16x8*>(
                    Ks + (t*16 + l16)*64 + (((s*4 + quad) ^ (l16 & 7))*8));
                sac[0][t] = __builtin_amdgcn_mfma_f32_16x16x32_bf16(kf, qf[0][s], sac[0][t], 0, 0, 0);
                sac[1][t] = __builtin_amdgcn_mfma_f32_16x16x32_bf16(kf, qf[1][s], sac[1][t], 0, 0, 0);
            }

        // P^T = exp2(S^T) in bf16, straight to registers (no max shift)
        short4v pk[2][8];
#pragma unroll
        for (int qg = 0; qg < 2; ++qg)
#pragma unroll
            for (int t = 0; t < 8; ++t) {
                bf16x4 pb;
#pragma unroll
                for (int r = 0; r < 4; ++r)
                    pb[r] = (__bf16)exp2f(sac[qg][t][r]);
                pk[qg][t] = __builtin_bit_cast(short4v, pb);
            }

        // O^T += V^T P^T ; td=4 accumulates the softmax denominator
#pragma unroll
        for (int td = 0; td < 5; ++td)
#pragma unroll
            for (int t = 0; t < 8; ++t) {
                short4v vf = *reinterpret_cast<const short4v*>(
                    Vs + (td*16 + l16)*128
                       + (((t*2 + (quad >> 1)) ^ l16) & 15)*8 + (quad & 1)*4);
                accO[0][td] = __builtin_amdgcn_mfma_f32_16x16x16bf16_1k(
                    vf, pk[0][t], accO[0][td], 0, 0, 0);
                accO[1][td] = __builtin_amdgcn_mfma_f32_16x16x16bf16_1k(
                    vf, pk[1][t], accO[1][td], 0, 0, 0);
            }
    }

    // epilogue: O = O^T / sum, write ao [B,N,H*64] bf16
#pragma unroll
    for (int qg = 0; qg < 2; ++qg) {
        float inv = 1.f / accO[qg][4][0];    // every lane holds its q's sum
        const size_t rowbase =
            (size_t)(blockIdx.z*2048 + q0 + qg*16 + l16)*1024 + blockIdx.y*64;
#pragma unroll
        for (int td = 0; td < 4; ++td)
#pragma unroll
            for (int r = 0; r < 4; ++r)
                ao[rowbase + td*16 + quad*4 + r] = f2bf(accO[qg][td][r] * inv);
    }
}

extern "C" void kernel_launch(void* const* d_in, const int* in_sizes, int n_in,
                              void* d_out, int out_size, void* d_ws, size_t ws_size,
                              hipStream_t stream)
{
    const float* x   = (const float*)d_in[0];
    const float* ctx = (const float*)d_in[1];
    const float* Wq  = (const float*)d_in[2];
    const float* Wk  = (const float*)d_in[3];
    const float* Wv  = (const float*)d_in[4];
    const float* Wo  = (const float*)d_in[5];
    const float* bo  = (const float*)d_in[6];
    float* out = (float*)d_out;

    unsigned short* ws  = (unsigned short*)d_ws;
    unsigned short* xb  = ws;
    unsigned short* cb  = ws + 4194304;
    unsigned short* wT  = ws + 8388608;
    unsigned short* qkv = ws + 12582912;
    unsigned short* ao  = ws;  // reuse xb space (xb dead after projections)

    prep<<<dim3(32, 32, 5), dim3(256), 0, stream>>>(x, ctx, Wq, Wk, Wv, Wo, xb, cb, wT);
    gemm128<<<dim3(8, 32, 3), dim3(256), 0, stream>>>(xb, cb, wT, ao, qkv, bo, out, 0);
    flash_attn<<<dim3(16, 16, 2), dim3(256), 0, stream>>>(qkv, qkv + 4194304, qkv + 8388608, ao);
    gemm128<<<dim3(8, 32, 1), dim3(256), 0, stream>>>(xb, cb, wT, ao, qkv, bo, out, 3);
}

// Round 4
// 224.307 us; speedup vs baseline: 1.3377x; 1.0396x over previous
//
#include <hip/hip_runtime.h>

// Problem constants
#define B_  2
#define N_  2048
#define M_  2048
#define D_  1024
#define H_  16
#define DH_ 64

typedef __bf16 bf16x8 __attribute__((ext_vector_type(8)));
typedef __bf16 bf16x4 __attribute__((ext_vector_type(4)));
typedef short  short4v __attribute__((ext_vector_type(4)));
typedef float  f32x4  __attribute__((ext_vector_type(4)));

#define GAS(p) ((__attribute__((address_space(1))) void*)(p))
#define LAS(p) ((__attribute__((address_space(3))) void*)(p))

// SCALE * log2(e), folded into Q at projection time
#define QPRESCALE 0.18033688011112042f

__device__ __forceinline__ unsigned short f2bf(float f) {
    unsigned int u = __builtin_bit_cast(unsigned int, f);
    u += 0x7fffu + ((u >> 16) & 1u);   // round-to-nearest-even
    return (unsigned short)(u >> 16);
}

// ------- kernel 1: prep = weight transpose+cast (z<4) | input cast (z==4) -------
__global__ __launch_bounds__(256) void prep(
    const float* __restrict__ x, const float* __restrict__ ctx,
    const float* __restrict__ Wq, const float* __restrict__ Wk,
    const float* __restrict__ Wv, const float* __restrict__ Wo,
    unsigned short* __restrict__ xb, unsigned short* __restrict__ cb,
    unsigned short* __restrict__ WTbase)
{
    if (blockIdx.z == 4) {
        int blk = blockIdx.y * 32 + blockIdx.x;
        int stride = 1024 * 256;
        for (int i = blk * 256 + threadIdx.x; i < 2097152; i += stride) {
            const float4* src; unsigned short* dst; int j;
            if (i < 1048576) { src = (const float4*)x;   dst = xb; j = i; }
            else             { src = (const float4*)ctx; dst = cb; j = i - 1048576; }
            float4 v = src[j];
            ushort4 o = make_ushort4(f2bf(v.x), f2bf(v.y), f2bf(v.z), f2bf(v.w));
            *(ushort4*)(dst + 4*j) = o;
        }
        return;
    }
    const float* W = (blockIdx.z == 0) ? Wq : (blockIdx.z == 1) ? Wk
                    : (blockIdx.z == 2) ? Wv : Wo;
    unsigned short* WT = WTbase + (size_t)blockIdx.z * 1048576;
    __shared__ unsigned short t[32][33];
    int tx = threadIdx.x & 31, ty8 = threadIdx.x >> 5;   // 32 x 8
    int c = blockIdx.x * 32 + tx;
#pragma unroll
    for (int i = 0; i < 4; ++i) {
        int r = blockIdx.y * 32 + i*8 + ty8;
        t[i*8 + ty8][tx] = f2bf(W[(size_t)r * 1024 + c]);
    }
    __syncthreads();
    int c2 = blockIdx.y * 32 + tx;
#pragma unroll
    for (int i = 0; i < 4; ++i) {
        int r2 = blockIdx.x * 32 + i*8 + ty8;
        WT[(size_t)r2 * 1024 + c2] = t[tx][i*8 + ty8];
    }
}

// ---------------- kernel 2/4: 128x128 bf16 GEMM, C = A * Bt^T ----------------
// mode 0: A=xb  -> Q*QPRESCALE stored [B,H,N,64] (bf16)
// mode 1: A=cb  -> K   stored [B,H,M,64]   (bf16)
// mode 2: A=cb  -> V^T stored [B,H,64,M]   (bf16)
// mode 3: A=ao  -> out fp32 [B,N,1024] + bias
__global__ __launch_bounds__(256) void gemm128(
    const unsigned short* __restrict__ xb,
    const unsigned short* __restrict__ cb,
    const unsigned short* __restrict__ wT,
    const unsigned short* __restrict__ aoA,
    unsigned short* __restrict__ qkv_out,
    const float* __restrict__ bo,
    float* __restrict__ outF,
    int base_mode)
{
    __shared__ __align__(16) unsigned short As[128*32];
    __shared__ __align__(16) unsigned short Bs[128*32];

    const int mode = base_mode + blockIdx.z;
    const unsigned short* Amat = (mode == 0) ? xb : (mode == 3) ? aoA : cb;
    const unsigned short* Bt = wT + (size_t)mode * 1048576;

    const int tid = threadIdx.x;
    const int w = tid >> 6, l = tid & 63;
    const int quad = l >> 4, l16 = l & 15;
    const int wm = w & 1, wn = w >> 1;
    const int row0 = blockIdx.y * 128, col0 = blockIdx.x * 128;

    f32x4 acc[4][4];
#pragma unroll
    for (int i = 0; i < 4; ++i)
#pragma unroll
        for (int j = 0; j < 4; ++j) acc[i][j] = (f32x4){0.f, 0.f, 0.f, 0.f};

    for (int k0 = 0; k0 < 1024; k0 += 32) {
        __syncthreads();
#pragma unroll
        for (int i = 0; i < 2; ++i) {
            int s = i*256 + w*64 + l;
            int m = s >> 2, c = s & 3;
            int cs = c ^ ((m >> 1) & 3);
            __builtin_amdgcn_global_load_lds(
                GAS(Amat + (size_t)(row0 + m)*1024 + k0 + cs*8),
                LAS(As + (i*256 + w*64)*8), 16, 0, 0);
            __builtin_amdgcn_global_load_lds(
                GAS(Bt + (size_t)(col0 + m)*1024 + k0 + cs*8),
                LAS(Bs + (i*256 + w*64)*8), 16, 0, 0);
        }
        __syncthreads();

        bf16x8 af[4], bfr[4];
#pragma unroll
        for (int mt = 0; mt < 4; ++mt) {
            int m = wm*64 + mt*16 + l16;
            af[mt] = *reinterpret_cast<const bf16x8*>(As + m*32 + (quad ^ ((m >> 1) & 3))*8);
            int n = wn*64 + mt*16 + l16;
            bfr[mt] = *reinterpret_cast<const bf16x8*>(Bs + n*32 + (quad ^ ((n >> 1) & 3))*8);
        }
#pragma unroll
        for (int mt = 0; mt < 4; ++mt)
#pragma unroll
            for (int nt = 0; nt < 4; ++nt)
                acc[mt][nt] = __builtin_amdgcn_mfma_f32_16x16x32_bf16(
                    af[mt], bfr[nt], acc[mt][nt], 0, 0, 0);
    }

    if (mode == 3) {
#pragma unroll
        for (int nt = 0; nt < 4; ++nt) {
            int col = col0 + wn*64 + nt*16 + l16;
            float bv = bo[col];
#pragma unroll
            for (int mt = 0; mt < 4; ++mt) {
                int gr = row0 + wm*64 + mt*16 + quad*4;
#pragma unroll
                for (int r = 0; r < 4; ++r)
                    outF[(size_t)(gr + r)*1024 + col] = acc[mt][nt][r] + bv;
            }
        }
    } else if (mode == 2) {
        // V^T: [B,H,64,M]
#pragma unroll
        for (int mt = 0; mt < 4; ++mt) {
            int gr = row0 + wm*64 + mt*16 + quad*4;
            int b = gr >> 11, nidx = gr & 2047;
#pragma unroll
            for (int nt = 0; nt < 4; ++nt) {
                int col = col0 + wn*64 + nt*16 + l16;
                int h = col >> 6, d = col & 63;
                ushort4 pk = make_ushort4(f2bf(acc[mt][nt][0]), f2bf(acc[mt][nt][1]),
                                          f2bf(acc[mt][nt][2]), f2bf(acc[mt][nt][3]));
                *(ushort4*)(qkv_out + (size_t)2*4194304
                            + (size_t)((b*16 + h)*64 + d)*2048 + nidx) = pk;
            }
        }
    } else {
        // Q/K: [B,H,seq,64]; Q is pre-scaled by SCALE*log2(e)
        const float qs = (mode == 0) ? QPRESCALE : 1.0f;
#pragma unroll
        for (int mt = 0; mt < 4; ++mt) {
            int gr = row0 + wm*64 + mt*16 + quad*4;
#pragma unroll
            for (int nt = 0; nt < 4; ++nt) {
                int col = col0 + wn*64 + nt*16 + l16;
                int h = col >> 6, d = col & 63;
#pragma unroll
                for (int r = 0; r < 4; ++r) {
                    int grr = gr + r;
                    int b = grr >> 11, nidx = grr & 2047;
                    qkv_out[(size_t)mode*4194304
                            + (size_t)((b*16 + h)*2048 + nidx)*64 + d]
                        = f2bf(acc[mt][nt][r] * qs);
                }
            }
        }
    }
}

// ---------------- kernel 3: flash attention ----------------
// S^T = K Q^T (C-layout == 16x16x16 B-frag layout) -> P^T feeds O^T = V^T P^T
// straight from registers.  Shift-free softmax (Q carries SCALE*log2e);
// denominator via MFMA against 16 ones-rows appended to V^T tile.
// LDS layouts PADDED (K rows 144B, V rows 272B) instead of XOR-swizzled:
// bank stride 4 (<=2-way), and V-frag reads become base + t*32B constant
// offsets so the compiler can merge pairs into ds_read2_b64.
__global__ __launch_bounds__(256, 2) void flash_attn(
    const unsigned short* __restrict__ qw,   // [B,H,N,64]  (pre-scaled)
    const unsigned short* __restrict__ kw,   // [B,H,M,64]
    const unsigned short* __restrict__ vtw,  // [B,H,64,M]
    unsigned short* __restrict__ ao)         // [B,N,H*64]
{
    // K tile: 128 rows x (64 data + 8 pad) ushorts = 144B rows, 9 chunks/row
    // V tile: 80 rows x (128 data + 8 pad) ushorts = 272B rows, 17 chunks/row
    //         rows 64..79 = 1.0 (softmax-sum tile)
    __shared__ __align__(16) unsigned short Ks[128*72];   // 18432 B
    __shared__ __align__(16) unsigned short Vs[80*136];   // 21760 B

    const int tid = threadIdx.x;
    const int w = tid >> 6, l = tid & 63;
    const int quad = l >> 4, l16 = l & 15;
    const int bh = blockIdx.z * H_ + blockIdx.y;
    const int q0 = blockIdx.x * 128 + w * 32;   // this wave's 32 queries

    // ones rows (sum tile): ushort offset 64*136 = 8704, 2176 ushorts = 272x16B
    {
        const unsigned int ONE2 = 0x3F803F80u;
        uint4* p = (uint4*)(Vs + 8704);
        p[tid] = make_uint4(ONE2, ONE2, ONE2, ONE2);
        if (tid < 16) p[256 + tid] = make_uint4(ONE2, ONE2, ONE2, ONE2);
    }

    // ---- precompute staging slot -> (row, chunk) decompositions (loop-invariant)
    // K: 1152 slots (9 chunks/row); rounds i=0..4, round 4 active for waves 0,1
    // V: 1088 slots (17 chunks/row); rounds i=0..4, round 4 active for wave 0
    int koff[5], voff[5];
#pragma unroll
    for (int i = 0; i < 5; ++i) {
        int n = i*256 + w*64 + l;
        int kv = n / 9, ck = n % 9;  if (ck > 7)  ck = 7;    // clamp pad chunk
        koff[i] = kv*64 + ck*8;                              // ushort offset, row stride 64
        int d  = n / 17, cv = n % 17; if (cv > 15) cv = 15;
        voff[i] = d*2048 + cv*8;                             // ushort offset, row stride 2048
    }
    const int kact4 = (w < 2), vact4 = (w < 1);

    // Q as B-frag (K=32): B[n=q][k=d]; two 16-q groups
    bf16x8 qf[2][2];
#pragma unroll
    for (int qg = 0; qg < 2; ++qg)
#pragma unroll
        for (int s = 0; s < 2; ++s)
            qf[qg][s] = *reinterpret_cast<const bf16x8*>(
                qw + (size_t)(bh*2048 + q0 + qg*16 + l16)*64 + s*32 + quad*8);

    f32x4 accO[2][5];   // [qg][td]; td=4 is the softmax-sum tile
#pragma unroll
    for (int qg = 0; qg < 2; ++qg)
#pragma unroll
        for (int td = 0; td < 5; ++td) accO[qg][td] = (f32x4){0.f, 0.f, 0.f, 0.f};

    const f32x4 zz = (f32x4){0.f, 0.f, 0.f, 0.f};

    for (int kv0 = 0; kv0 < M_; kv0 += 128) {
        const unsigned short* kp = kw + (size_t)bh*131072 + kv0*64;
        const unsigned short* vp = vtw + (size_t)bh*131072 + kv0;
        __syncthreads();
#pragma unroll
        for (int i = 0; i < 4; ++i)
            __builtin_amdgcn_global_load_lds(GAS(kp + koff[i]),
                LAS(Ks + (i*256 + w*64)*8), 16, 0, 0);
        if (kact4)
            __builtin_amdgcn_global_load_lds(GAS(kp + koff[4]),
                LAS(Ks + (1024 + w*64)*8), 16, 0, 0);
#pragma unroll
        for (int i = 0; i < 4; ++i)
            __builtin_amdgcn_global_load_lds(GAS(vp + voff[i]),
                LAS(Vs + (i*256 + w*64)*8), 16, 0, 0);
        if (vact4)
            __builtin_amdgcn_global_load_lds(GAS(vp + voff[4]),
                LAS(Vs + (1024 + w*64)*8), 16, 0, 0);
        __syncthreads();

        // S^T = K Q^T : A = K-frag (m=kv), B = Q-frag (n=q)
        // first MFMA takes hoisted zero C -> no per-iter acc zero-init
        f32x4 sac[2][8];
#pragma unroll
        for (int t = 0; t < 8; ++t) {
            const unsigned short* krow = Ks + (t*16 + l16)*72 + quad*8;
            bf16x8 kf0 = *reinterpret_cast<const bf16x8*>(krow);
            bf16x8 kf1 = *reinterpret_cast<const bf16x8*>(krow + 32);
            sac[0][t] = __builtin_amdgcn_mfma_f32_16x16x32_bf16(kf0, qf[0][0], zz, 0, 0, 0);
            sac[1][t] = __builtin_amdgcn_mfma_f32_16x16x32_bf16(kf0, qf[1][0], zz, 0, 0, 0);
            sac[0][t] = __builtin_amdgcn_mfma_f32_16x16x32_bf16(kf1, qf[0][1], sac[0][t], 0, 0, 0);
            sac[1][t] = __builtin_amdgcn_mfma_f32_16x16x32_bf16(kf1, qf[1][1], sac[1][t], 0, 0, 0);
        }

        // P^T = exp2(S^T) in bf16 (raw v_exp_f32), straight to registers
        short4v pk[2][8];
#pragma unroll
        for (int qg = 0; qg < 2; ++qg)
#pragma unroll
            for (int t = 0; t < 8; ++t) {
                bf16x4 pb;
#pragma unroll
                for (int r = 0; r < 4; ++r)
                    pb[r] = (__bf16)__builtin_amdgcn_exp2f(sac[qg][t][r]);
                pk[qg][t] = __builtin_bit_cast(short4v, pb);
            }

        // O^T += V^T P^T ; td=4 accumulates the softmax denominator.
        // V-frag: A[m=d][k=quad*4+j] -> row*(136) + quad*4 + t*16 (const offsets)
#pragma unroll
        for (int td = 0; td < 5; ++td) {
            const unsigned short* vrow = Vs + (td*16 + l16)*136 + quad*4;
#pragma unroll
            for (int t = 0; t < 8; ++t) {
                short4v vf = *reinterpret_cast<const short4v*>(vrow + t*16);
                accO[0][td] = __builtin_amdgcn_mfma_f32_16x16x16bf16_1k(
                    vf, pk[0][t], accO[0][td], 0, 0, 0);
                accO[1][td] = __builtin_amdgcn_mfma_f32_16x16x16bf16_1k(
                    vf, pk[1][t], accO[1][td], 0, 0, 0);
            }
        }
    }

    // epilogue: O = O^T / sum, write ao [B,N,H*64] bf16
#pragma unroll
    for (int qg = 0; qg < 2; ++qg) {
        float inv = 1.f / accO[qg][4][0];    // every lane holds its q's sum
        const size_t rowbase =
            (size_t)(blockIdx.z*2048 + q0 + qg*16 + l16)*1024 + blockIdx.y*64;
#pragma unroll
        for (int td = 0; td < 4; ++td)
#pragma unroll
            for (int r = 0; r < 4; ++r)
                ao[rowbase + td*16 + quad*4 + r] = f2bf(accO[qg][td][r] * inv);
    }
}

extern "C" void kernel_launch(void* const* d_in, const int* in_sizes, int n_in,
                              void* d_out, int out_size, void* d_ws, size_t ws_size,
                              hipStream_t stream)
{
    const float* x   = (const float*)d_in[0];
    const float* ctx = (const float*)d_in[1];
    const float* Wq  = (const float*)d_in[2];
    const float* Wk  = (const float*)d_in[3];
    const float* Wv  = (const float*)d_in[4];
    const float* Wo  = (const float*)d_in[5];
    const float* bo  = (const float*)d_in[6];
    float* out = (float*)d_out;

    unsigned short* ws  = (unsigned short*)d_ws;
    unsigned short* xb  = ws;
    unsigned short* cb  = ws + 4194304;
    unsigned short* wT  = ws + 8388608;
    unsigned short* qkv = ws + 12582912;
    unsigned short* ao  = ws;  // reuse xb space (xb dead after projections)

    prep<<<dim3(32, 32, 5), dim3(256), 0, stream>>>(x, ctx, Wq, Wk, Wv, Wo, xb, cb, wT);
    gemm128<<<dim3(8, 32, 3), dim3(256), 0, stream>>>(xb, cb, wT, ao, qkv, bo, out, 0);
    flash_attn<<<dim3(16, 16, 2), dim3(256), 0, stream>>>(qkv, qkv + 4194304, qkv + 8388608, ao);
    gemm128<<<dim3(8, 32, 1), dim3(256), 0, stream>>>(xb, cb, wT, ao, qkv, bo, out, 3);
}

// Round 5
// 222.566 us; speedup vs baseline: 1.3482x; 1.0078x over previous
//
#include <hip/hip_runtime.h>

// Problem constants
#define B_  2
#define N_  2048
#define M_  2048
#define D_  1024
#define H_  16
#define DH_ 64

typedef __bf16 bf16x8 __attribute__((ext_vector_type(8)));
typedef __bf16 bf16x4 __attribute__((ext_vector_type(4)));
typedef short  short4v __attribute__((ext_vector_type(4)));
typedef float  f32x4  __attribute__((ext_vector_type(4)));

#define GAS(p) ((__attribute__((address_space(1))) void*)(p))
#define LAS(p) ((__attribute__((address_space(3))) void*)(p))

// SCALE * log2(e), folded into Q at projection time
#define QPRESCALE 0.18033688011112042f

__device__ __forceinline__ unsigned short f2bf(float f) {
    unsigned int u = __builtin_bit_cast(unsigned int, f);
    u += 0x7fffu + ((u >> 16) & 1u);   // round-to-nearest-even
    return (unsigned short)(u >> 16);
}

// ------- kernel 1: prep = weight transpose+cast (z<4) | input cast (z==4) -------
__global__ __launch_bounds__(256) void prep(
    const float* __restrict__ x, const float* __restrict__ ctx,
    const float* __restrict__ Wq, const float* __restrict__ Wk,
    const float* __restrict__ Wv, const float* __restrict__ Wo,
    unsigned short* __restrict__ xb, unsigned short* __restrict__ cb,
    unsigned short* __restrict__ WTbase)
{
    if (blockIdx.z == 4) {
        int blk = blockIdx.y * 32 + blockIdx.x;
        int stride = 1024 * 256;
        for (int i = blk * 256 + threadIdx.x; i < 2097152; i += stride) {
            const float4* src; unsigned short* dst; int j;
            if (i < 1048576) { src = (const float4*)x;   dst = xb; j = i; }
            else             { src = (const float4*)ctx; dst = cb; j = i - 1048576; }
            float4 v = src[j];
            ushort4 o = make_ushort4(f2bf(v.x), f2bf(v.y), f2bf(v.z), f2bf(v.w));
            *(ushort4*)(dst + 4*j) = o;
        }
        return;
    }
    const float* W = (blockIdx.z == 0) ? Wq : (blockIdx.z == 1) ? Wk
                    : (blockIdx.z == 2) ? Wv : Wo;
    unsigned short* WT = WTbase + (size_t)blockIdx.z * 1048576;
    __shared__ unsigned short t[32][33];
    int tx = threadIdx.x & 31, ty8 = threadIdx.x >> 5;   // 32 x 8
    int c = blockIdx.x * 32 + tx;
#pragma unroll
    for (int i = 0; i < 4; ++i) {
        int r = blockIdx.y * 32 + i*8 + ty8;
        t[i*8 + ty8][tx] = f2bf(W[(size_t)r * 1024 + c]);
    }
    __syncthreads();
    int c2 = blockIdx.y * 32 + tx;
#pragma unroll
    for (int i = 0; i < 4; ++i) {
        int r2 = blockIdx.x * 32 + i*8 + ty8;
        WT[(size_t)r2 * 1024 + c2] = t[tx][i*8 + ty8];
    }
}

// ---------------- kernel 2/4: 128x128 bf16 GEMM, C = A * Bt^T ----------------
// mode 0: A=xb  -> Q*QPRESCALE stored [B,H,N,64] (bf16)
// mode 1: A=cb  -> K   stored [B,H,M,64]   (bf16)
// mode 2: A=cb  -> V^T stored [B,H,64,M]   (bf16)
// mode 3: A=ao  -> out fp32 [B,N,1024] + bias
__global__ __launch_bounds__(256) void gemm128(
    const unsigned short* __restrict__ xb,
    const unsigned short* __restrict__ cb,
    const unsigned short* __restrict__ wT,
    const unsigned short* __restrict__ aoA,
    unsigned short* __restrict__ qkv_out,
    const float* __restrict__ bo,
    float* __restrict__ outF,
    int base_mode)
{
    __shared__ __align__(16) unsigned short As[128*32];
    __shared__ __align__(16) unsigned short Bs[128*32];

    const int mode = base_mode + blockIdx.z;
    const unsigned short* Amat = (mode == 0) ? xb : (mode == 3) ? aoA : cb;
    const unsigned short* Bt = wT + (size_t)mode * 1048576;

    const int tid = threadIdx.x;
    const int w = tid >> 6, l = tid & 63;
    const int quad = l >> 4, l16 = l & 15;
    const int wm = w & 1, wn = w >> 1;
    const int row0 = blockIdx.y * 128, col0 = blockIdx.x * 128;

    f32x4 acc[4][4];
#pragma unroll
    for (int i = 0; i < 4; ++i)
#pragma unroll
        for (int j = 0; j < 4; ++j) acc[i][j] = (f32x4){0.f, 0.f, 0.f, 0.f};

    for (int k0 = 0; k0 < 1024; k0 += 32) {
        __syncthreads();
#pragma unroll
        for (int i = 0; i < 2; ++i) {
            int s = i*256 + w*64 + l;
            int m = s >> 2, c = s & 3;
            int cs = c ^ ((m >> 1) & 3);
            __builtin_amdgcn_global_load_lds(
                GAS(Amat + (size_t)(row0 + m)*1024 + k0 + cs*8),
                LAS(As + (i*256 + w*64)*8), 16, 0, 0);
            __builtin_amdgcn_global_load_lds(
                GAS(Bt + (size_t)(col0 + m)*1024 + k0 + cs*8),
                LAS(Bs + (i*256 + w*64)*8), 16, 0, 0);
        }
        __syncthreads();

        bf16x8 af[4], bfr[4];
#pragma unroll
        for (int mt = 0; mt < 4; ++mt) {
            int m = wm*64 + mt*16 + l16;
            af[mt] = *reinterpret_cast<const bf16x8*>(As + m*32 + (quad ^ ((m >> 1) & 3))*8);
            int n = wn*64 + mt*16 + l16;
            bfr[mt] = *reinterpret_cast<const bf16x8*>(Bs + n*32 + (quad ^ ((n >> 1) & 3))*8);
        }
#pragma unroll
        for (int mt = 0; mt < 4; ++mt)
#pragma unroll
            for (int nt = 0; nt < 4; ++nt)
                acc[mt][nt] = __builtin_amdgcn_mfma_f32_16x16x32_bf16(
                    af[mt], bfr[nt], acc[mt][nt], 0, 0, 0);
    }

    if (mode == 3) {
#pragma unroll
        for (int nt = 0; nt < 4; ++nt) {
            int col = col0 + wn*64 + nt*16 + l16;
            float bv = bo[col];
#pragma unroll
            for (int mt = 0; mt < 4; ++mt) {
                int gr = row0 + wm*64 + mt*16 + quad*4;
#pragma unroll
                for (int r = 0; r < 4; ++r)
                    outF[(size_t)(gr + r)*1024 + col] = acc[mt][nt][r] + bv;
            }
        }
    } else if (mode == 2) {
        // V^T: [B,H,64,M]
#pragma unroll
        for (int mt = 0; mt < 4; ++mt) {
            int gr = row0 + wm*64 + mt*16 + quad*4;
            int b = gr >> 11, nidx = gr & 2047;
#pragma unroll
            for (int nt = 0; nt < 4; ++nt) {
                int col = col0 + wn*64 + nt*16 + l16;
                int h = col >> 6, d = col & 63;
                ushort4 pk = make_ushort4(f2bf(acc[mt][nt][0]), f2bf(acc[mt][nt][1]),
                                          f2bf(acc[mt][nt][2]), f2bf(acc[mt][nt][3]));
                *(ushort4*)(qkv_out + (size_t)2*4194304
                            + (size_t)((b*16 + h)*64 + d)*2048 + nidx) = pk;
            }
        }
    } else {
        // Q/K: [B,H,seq,64]; Q is pre-scaled by SCALE*log2(e)
        const float qs = (mode == 0) ? QPRESCALE : 1.0f;
#pragma unroll
        for (int mt = 0; mt < 4; ++mt) {
            int gr = row0 + wm*64 + mt*16 + quad*4;
#pragma unroll
            for (int nt = 0; nt < 4; ++nt) {
                int col = col0 + wn*64 + nt*16 + l16;
                int h = col >> 6, d = col & 63;
#pragma unroll
                for (int r = 0; r < 4; ++r) {
                    int grr = gr + r;
                    int b = grr >> 11, nidx = grr & 2047;
                    qkv_out[(size_t)mode*4194304
                            + (size_t)((b*16 + h)*2048 + nidx)*64 + d]
                        = f2bf(acc[mt][nt][r] * qs);
                }
            }
        }
    }
}

// ---------------- kernel 3: flash attention (double-buffered) ----------------
// q-tile 128 (4 waves x 32 q), KV-tile 64, LDS double-buffered.
// Pipeline: barrier -> issue global_load_lds(tile i+1 -> buf^1) -> compute(buf).
// The compiler's vmcnt(0)-before-barrier drain then waits on loads that had a
// full compute phase in flight.  Unified K|V slot space per tile:
//   slots [0,576)   = K  64 rows x 9 chunks (72-ushort rows, 8-ushort pad)
//   slots [576,1152)= V^T 64 rows x 9 chunks (72-ushort rows)
// Softmax denominator: per-lane fp32 adds of exp values accumulated across
// iters; 2 shuffles total at the end.  Shift-free (Q carries SCALE*log2e).
__global__ __launch_bounds__(256, 2) void flash_attn(
    const unsigned short* __restrict__ qw,   // [B,H,N,64]  (pre-scaled)
    const unsigned short* __restrict__ kw,   // [B,H,M,64]
    const unsigned short* __restrict__ vtw,  // [B,H,64,M]
    unsigned short* __restrict__ ao)         // [B,N,H*64]
{
    __shared__ __align__(16) unsigned short Tile[2][9216];  // 2 x 18432 B

    const int tid = threadIdx.x;
    const int w = tid >> 6, l = tid & 63;
    const int quad = l >> 4, l16 = l & 15;
    const int bh = blockIdx.z * H_ + blockIdx.y;
    const int q0 = blockIdx.x * 128 + w * 32;   // this wave's 32 queries

    // staging decomposition (loop-invariant): slot n = i*256 + w*64 + l
    // region (K/V) is wave-uniform per round: K iff i*4 + w < 9
    int goff[5];
#pragma unroll
    for (int i = 0; i < 5; ++i) {
        int n = i*256 + w*64 + l;
        int m = (n < 576) ? n : n - 576;
        int row = m / 9, c = m % 9;  if (c > 7) c = 7;     // clamp pad chunk
        goff[i] = (n < 576) ? row*64 + c*8 : row*2048 + c*8;
    }
    const unsigned short* kbase = kw + (size_t)bh*131072;
    const unsigned short* vbase = vtw + (size_t)bh*131072;

    // Q as B-frag (K=32): B[n=q][k=d]; two 16-q groups
    bf16x8 qf[2][2];
#pragma unroll
    for (int qg = 0; qg < 2; ++qg)
#pragma unroll
        for (int s = 0; s < 2; ++s)
            qf[qg][s] = *reinterpret_cast<const bf16x8*>(
                qw + (size_t)(bh*2048 + q0 + qg*16 + l16)*64 + s*32 + quad*8);

    f32x4 accO[2][4];
#pragma unroll
    for (int qg = 0; qg < 2; ++qg)
#pragma unroll
        for (int td = 0; td < 4; ++td) accO[qg][td] = (f32x4){0.f, 0.f, 0.f, 0.f};
    float lpart[2] = {0.f, 0.f};

    const f32x4 zz = (f32x4){0.f, 0.f, 0.f, 0.f};

    // ---- preload tile 0 into buf 0
    {
#pragma unroll
        for (int i = 0; i < 4; ++i) {
            const unsigned short* bp = (i*4 + w < 9) ? kbase : vbase;
            __builtin_amdgcn_global_load_lds(GAS(bp + goff[i]),
                LAS(&Tile[0][(i*256 + w*64)*8]), 16, 0, 0);
        }
        if (w < 2)
            __builtin_amdgcn_global_load_lds(GAS(vbase + goff[4]),
                LAS(&Tile[0][(1024 + w*64)*8]), 16, 0, 0);
    }

    for (int it = 0; it < 32; ++it) {
        __syncthreads();   // drains vmcnt -> Tile[it&1] ready; prev reads of Tile[!cur] done
        const int cur = it & 1;

        if (it + 1 < 32) {
            const unsigned short* kp = kbase + (it+1)*4096;
            const unsigned short* vp = vbase + (it+1)*64;
#pragma unroll
            for (int i = 0; i < 4; ++i) {
                const unsigned short* bp = (i*4 + w < 9) ? kp : vp;
                __builtin_amdgcn_global_load_lds(GAS(bp + goff[i]),
                    LAS(&Tile[cur^1][(i*256 + w*64)*8]), 16, 0, 0);
            }
            if (w < 2)
                __builtin_amdgcn_global_load_lds(GAS(vp + goff[4]),
                    LAS(&Tile[cur^1][(1024 + w*64)*8]), 16, 0, 0);
        }

        const unsigned short* Ks = &Tile[cur][0];
        const unsigned short* Vs = &Tile[cur][4608];

        // S^T = K Q^T : A = K-frag (m=kv), B = Q-frag (n=q); zero-C first MFMA
        f32x4 sac[2][4];
#pragma unroll
        for (int t = 0; t < 4; ++t) {
            const unsigned short* krow = Ks + (t*16 + l16)*72 + quad*8;
            bf16x8 kf0 = *reinterpret_cast<const bf16x8*>(krow);
            bf16x8 kf1 = *reinterpret_cast<const bf16x8*>(krow + 32);
            sac[0][t] = __builtin_amdgcn_mfma_f32_16x16x32_bf16(kf0, qf[0][0], zz, 0, 0, 0);
            sac[1][t] = __builtin_amdgcn_mfma_f32_16x16x32_bf16(kf0, qf[1][0], zz, 0, 0, 0);
            sac[0][t] = __builtin_amdgcn_mfma_f32_16x16x32_bf16(kf1, qf[0][1], sac[0][t], 0, 0, 0);
            sac[1][t] = __builtin_amdgcn_mfma_f32_16x16x32_bf16(kf1, qf[1][1], sac[1][t], 0, 0, 0);
        }

        // P^T = exp2(S^T) (raw v_exp_f32); per-lane fp32 partial row-sums
        short4v pk[2][4];
#pragma unroll
        for (int qg = 0; qg < 2; ++qg) {
            float s0 = 0.f, s1 = 0.f, s2 = 0.f, s3 = 0.f;
#pragma unroll
            for (int t = 0; t < 4; ++t) {
                float p0 = __builtin_amdgcn_exp2f(sac[qg][t][0]);
                float p1 = __builtin_amdgcn_exp2f(sac[qg][t][1]);
                float p2 = __builtin_amdgcn_exp2f(sac[qg][t][2]);
                float p3 = __builtin_amdgcn_exp2f(sac[qg][t][3]);
                s0 += p0; s1 += p1; s2 += p2; s3 += p3;
                bf16x4 pb;
                pb[0] = (__bf16)p0; pb[1] = (__bf16)p1;
                pb[2] = (__bf16)p2; pb[3] = (__bf16)p3;
                pk[qg][t] = __builtin_bit_cast(short4v, pb);
            }
            lpart[qg] += (s0 + s1) + (s2 + s3);
        }

        // O^T += V^T P^T : A = V^T-frag (m=d, k=kv), B = P^T (registers)
#pragma unroll
        for (int td = 0; td < 4; ++td) {
            const unsigned short* vrow = Vs + (td*16 + l16)*72 + quad*4;
#pragma unroll
            for (int t = 0; t < 4; ++t) {
                short4v vf = *reinterpret_cast<const short4v*>(vrow + t*16);
                accO[0][td] = __builtin_amdgcn_mfma_f32_16x16x16bf16_1k(
                    vf, pk[0][t], accO[0][td], 0, 0, 0);
                accO[1][td] = __builtin_amdgcn_mfma_f32_16x16x16bf16_1k(
                    vf, pk[1][t], accO[1][td], 0, 0, 0);
            }
        }
    }

    // epilogue: reduce denominator across quads (kv partials), normalize, store
#pragma unroll
    for (int qg = 0; qg < 2; ++qg) {
        float s = lpart[qg];
        s += __shfl_xor(s, 16);
        s += __shfl_xor(s, 32);
        float inv = 1.f / s;
        const size_t rowbase =
            (size_t)(blockIdx.z*2048 + q0 + qg*16 + l16)*1024 + blockIdx.y*64;
#pragma unroll
        for (int td = 0; td < 4; ++td)
#pragma unroll
            for (int r = 0; r < 4; ++r)
                ao[rowbase + td*16 + quad*4 + r] = f2bf(accO[qg][td][r] * inv);
    }
}

extern "C" void kernel_launch(void* const* d_in, const int* in_sizes, int n_in,
                              void* d_out, int out_size, void* d_ws, size_t ws_size,
                              hipStream_t stream)
{
    const float* x   = (const float*)d_in[0];
    const float* ctx = (const float*)d_in[1];
    const float* Wq  = (const float*)d_in[2];
    const float* Wk  = (const float*)d_in[3];
    const float* Wv  = (const float*)d_in[4];
    const float* Wo  = (const float*)d_in[5];
    const float* bo  = (const float*)d_in[6];
    float* out = (float*)d_out;

    unsigned short* ws  = (unsigned short*)d_ws;
    unsigned short* xb  = ws;
    unsigned short* cb  = ws + 4194304;
    unsigned short* wT  = ws + 8388608;
    unsigned short* qkv = ws + 12582912;
    unsigned short* ao  = ws;  // reuse xb space (xb dead after projections)

    prep<<<dim3(32, 32, 5), dim3(256), 0, stream>>>(x, ctx, Wq, Wk, Wv, Wo, xb, cb, wT);
    gemm128<<<dim3(8, 32, 3), dim3(256), 0, stream>>>(xb, cb, wT, ao, qkv, bo, out, 0);
    flash_attn<<<dim3(16, 16, 2), dim3(256), 0, stream>>>(qkv, qkv + 4194304, qkv + 8388608, ao);
    gemm128<<<dim3(8, 32, 1), dim3(256), 0, stream>>>(xb, cb, wT, ao, qkv, bo, out, 3);
}